// Round 3
// baseline (546.693 us; speedup 1.0000x reference)
//
#include <hip/hip_runtime.h>
#include <hip/hip_cooperative_groups.h>
#include <math.h>

namespace cg = cooperative_groups;

#define EPSB 1e-5f

constexpr int N_ = 64, C_ = 256, T_ = 64, V_ = 25, C4_ = 64;
constexpr int NC = N_ * C_;   // 16384
constexpr int TV = T_ * V_;   // 1600

// LDS overlay: phases use disjoint time windows (grid.sync between).
union SMemU {
    float pool[4 * TV];                       // phase 1: 25.6 KB
    float Wt[64 * 130];                       // phase 2 G: 33.3 KB
    struct { float ps[C_ * 18]; float a1s[C4_ * 17]; } L;  // phase 2 L: 22.8 KB
};

// ================= fused cooperative kernel =================
__global__ __launch_bounds__(256, 4) void kfused(
    const float* __restrict__ x, const float* __restrict__ Wg1,
    const float* __restrict__ g1, const float* __restrict__ b1,
    const float* __restrict__ m1, const float* __restrict__ v1,
    const float* __restrict__ Wg2, const float* __restrict__ WL1,
    const float* __restrict__ g2, const float* __restrict__ b2,
    const float* __restrict__ m2, const float* __restrict__ v2,
    const float* __restrict__ WL2, float* __restrict__ out,
    float* __restrict__ pooled, float* __restrict__ act,
    float* __restrict__ kern) {
    __shared__ SMemU sm;
    const int tid = threadIdx.x;
    const int bid = blockIdx.x;
    const int nB = gridDim.x;
    cg::grid_group grid = cg::this_grid();

    // ---------- phase 1: pooled[nc][t] = mean_v x ----------
    for (int g = bid; g < NC / 4; g += nB) {
        const float4* xp4 = (const float4*)(x + (size_t)g * (4 * TV));
        float4* s4 = (float4*)sm.pool;
        for (int f = tid; f < TV; f += 256) s4[f] = xp4[f];
        __syncthreads();
        float s = 0.f;
        const int base = tid * 25;
#pragma unroll
        for (int v = 0; v < 25; ++v) s += sm.pool[base + v];
        pooled[(size_t)g * 256 + tid] = s * (1.0f / 25.0f);
        __syncthreads();
    }
    grid.sync();

    // ---------- phase 2: role-split (3/4 blocks -> G, 1/4 -> L) ----------
    const int role = bid & 3;
    const int lane = tid & 63;
    const int wv = tid >> 6;
    if (role < 3) {
        // ---- G branch ----
        for (int e = tid; e < 128 * 64; e += 256) {
            const int j = e >> 6, t = e & 63;
            sm.Wt[t * 130 + j] = Wg1[e];
        }
        __syncthreads();
        const int j0 = lane, j1 = lane + 64;
        const float s0 = g1[j0] * rsqrtf(v1[j0] + EPSB);
        const float s1 = g1[j1] * rsqrtf(v1[j1] + EPSB);
        const float c0 = b1[j0] - m1[j0] * s0;
        const float c1 = b1[j1] - m1[j1] * s1;
        const float wa0 = Wg2[j0], wa1 = Wg2[j1];
        const float wb0 = Wg2[128 + j0], wb1 = Wg2[128 + j1];
        const float wc0 = Wg2[256 + j0], wc1 = Wg2[256 + j1];
        const int Gbid = (bid >> 2) * 3 + role;
        const int gwid = Gbid * 4 + wv;
        const int nGw = (nB >> 2) * 12;
        for (int ch = gwid; ch < NC / 8; ch += nGw) {
            const int r0 = ch * 8;
            float pv[8], h0[8], h1[8];
#pragma unroll
            for (int r = 0; r < 8; ++r) {
                pv[r] = pooled[(size_t)(r0 + r) * 64 + lane];
                h0[r] = 0.f; h1[r] = 0.f;
            }
#pragma unroll
            for (int tb = 0; tb < 4; ++tb) {
                float w0[16], w1[16];
#pragma unroll
                for (int tt = 0; tt < 16; ++tt) {
                    w0[tt] = sm.Wt[(tb * 16 + tt) * 130 + j0];
                    w1[tt] = sm.Wt[(tb * 16 + tt) * 130 + j1];
                }
#pragma unroll
                for (int tt = 0; tt < 16; ++tt) {
#pragma unroll
                    for (int r = 0; r < 8; ++r) {
                        const float pt = __uint_as_float(
                            __builtin_amdgcn_readlane(__float_as_uint(pv[r]), tb * 16 + tt));
                        h0[r] = fmaf(w0[tt], pt, h0[r]);
                        h1[r] = fmaf(w1[tt], pt, h1[r]);
                    }
                }
            }
#pragma unroll
            for (int r = 0; r < 8; ++r) {
                const float a0 = fmaxf(fmaf(h0[r], s0, c0), 0.f);
                const float a1v = fmaxf(fmaf(h1[r], s1, c1), 0.f);
                float p0 = wa0 * a0 + wa1 * a1v;
                float p1 = wb0 * a0 + wb1 * a1v;
                float p2 = wc0 * a0 + wc1 * a1v;
#pragma unroll
                for (int off = 32; off > 0; off >>= 1) {
                    p0 += __shfl_xor(p0, off);
                    p1 += __shfl_xor(p1, off);
                    p2 += __shfl_xor(p2, off);
                }
                const float mx = fmaxf(p0, fmaxf(p1, p2));
                const float e0 = expf(p0 - mx), e1 = expf(p1 - mx), e2 = expf(p2 - mx);
                const float inv = 1.0f / (e0 + e1 + e2);
                if (lane < 3) {
                    const float val = (lane == 0) ? e0 : (lane == 1) ? e1 : e2;
                    kern[(size_t)(r0 + r) * 3 + lane] = val * inv;
                }
            }
        }
    } else {
        // ---- L branch: tiles (n, t-quarter) ----
        const int Lbid = bid >> 2;
        for (int tile = Lbid; tile < 256; tile += (nB >> 2)) {
            const int n = tile >> 2;
            const int t0 = (tile & 3) * 16;
            for (int e = tid; e < C_ * 18; e += 256) {
                const int i = e / 18, tt = e - i * 18;
                const int gt = t0 - 1 + tt;
                sm.L.ps[e] = (gt >= 0 && gt < 64)
                                 ? pooled[(size_t)n * 16384 + i * 64 + gt] : 0.f;
            }
            __syncthreads();
            const int tg = lane >> 4;     // 0..3
            const int t = lane & 15;
            const int ccb = wv * 16;
            float acc[4] = {0.f, 0.f, 0.f, 0.f};
            for (int i = 0; i < C_; ++i) {
                const float pm = sm.L.ps[i * 18 + t];
                const float pc = sm.L.ps[i * 18 + t + 1];
                const float pp = sm.L.ps[i * 18 + t + 2];
#pragma unroll
                for (int q = 0; q < 4; ++q) {
                    const float* wr = WL1 + (size_t)(ccb + q * 4 + tg) * 768 + i * 3;
                    acc[q] = fmaf(wr[0], pm, fmaf(wr[1], pc, fmaf(wr[2], pp, acc[q])));
                }
            }
#pragma unroll
            for (int q = 0; q < 4; ++q) {
                const int cc = ccb + q * 4 + tg;
                const float sc = g2[cc] * rsqrtf(v2[cc] + EPSB);
                const float sh = b2[cc] - m2[cc] * sc;
                sm.L.a1s[cc * 17 + t] = fmaxf(fmaf(acc[q], sc, sh), 0.f);
            }
            __syncthreads();
            // conv2 (k=1) + sigmoid: thread = output channel
            const int c = tid;
            float o[16];
#pragma unroll
            for (int q = 0; q < 16; ++q) o[q] = 0.f;
            const float* w2 = WL2 + (size_t)c * 64;
            for (int i = 0; i < 64; ++i) {
                const float w = w2[i];
#pragma unroll
                for (int q = 0; q < 16; ++q) o[q] = fmaf(w, sm.L.a1s[i * 17 + q], o[q]);
            }
            float* ar = act + ((size_t)n * 256 + c) * 64 + t0;
#pragma unroll
            for (int q = 0; q < 16; ++q) ar[q] = 1.0f / (1.0f + expf(-o[q]));
            __syncthreads();
        }
    }
    grid.sync();

    // ---------- phase 3: out = x + sum_k kern_k*(x*act)[t+k-1] ----------
    for (int row = bid; row < NC; row += nB) {
        const float* xr = x + (size_t)row * TV;
        const float* acr = act + (size_t)row * 64;
        float* outr = out + (size_t)row * TV;
        const float k0 = kern[(size_t)row * 3 + 0];
        const float k1 = kern[(size_t)row * 3 + 1];
        const float k2 = kern[(size_t)row * 3 + 2];
        for (int e = tid; e < TV; e += 256) {
            const int t = e / 25;
            const float xc = xr[e];
            const float xm = (t > 0) ? xr[e - 25] : 0.f;
            const float xq = (t < 63) ? xr[e + 25] : 0.f;
            const float am = (t > 0) ? acr[t - 1] : 0.f;
            const float ac = acr[t];
            const float ap = (t < 63) ? acr[t + 1] : 0.f;
            outr[e] = fmaf(k0, xm * am, fmaf(k1, xc * ac, fmaf(k2, xq * ap, xc)));
        }
    }
}

// ================= fallback path (round-2 kernels, known-good) =============
__global__ __launch_bounds__(256) void k_pool(const float* __restrict__ x,
                                              float* __restrict__ pooled) {
    __shared__ float xs[4 * TV];
    const int b = blockIdx.x;
    const float4* xp4 = (const float4*)(x + (size_t)b * (4 * TV));
    float4* xs4 = (float4*)xs;
    for (int f = threadIdx.x; f < TV; f += 256) xs4[f] = xp4[f];
    __syncthreads();
    float s = 0.f;
    const int base = threadIdx.x * V_;
#pragma unroll
    for (int v = 0; v < V_; ++v) s += xs[base + v];
    pooled[(size_t)b * 256 + threadIdx.x] = s * (1.0f / 25.0f);
}

__global__ __launch_bounds__(256) void k_gbranch(
    const float* __restrict__ pooled, const float* __restrict__ Wg1,
    const float* __restrict__ g1, const float* __restrict__ b1,
    const float* __restrict__ m1, const float* __restrict__ v1,
    const float* __restrict__ Wg2, float* __restrict__ kern) {
    __shared__ float Wt[T_ * 130];
    for (int e = threadIdx.x; e < 128 * T_; e += 256) {
        const int j = e >> 6, t = e & 63;
        Wt[t * 130 + j] = Wg1[e];
    }
    __syncthreads();
    const int lane = threadIdx.x & 63;
    const int gw = blockIdx.x * 4 + (threadIdx.x >> 6);
    const int j0 = lane, j1 = lane + 64;
    float w0[T_], w1[T_];
#pragma unroll
    for (int t = 0; t < T_; ++t) {
        w0[t] = Wt[t * 130 + j0];
        w1[t] = Wt[t * 130 + j1];
    }
    const float s0 = g1[j0] * rsqrtf(v1[j0] + EPSB);
    const float s1 = g1[j1] * rsqrtf(v1[j1] + EPSB);
    const float c0 = b1[j0] - m1[j0] * s0;
    const float c1 = b1[j1] - m1[j1] * s1;
    const float wa0 = Wg2[j0], wa1 = Wg2[j1];
    const float wb0 = Wg2[128 + j0], wb1 = Wg2[128 + j1];
    const float wc0 = Wg2[256 + j0], wc1 = Wg2[256 + j1];
    for (int rr = 0; rr < 8; ++rr) {
        const int row = __builtin_amdgcn_readfirstlane(gw * 8 + rr);
        const float* __restrict__ prow = pooled + (size_t)row * T_;
        float h0 = 0.f, h1 = 0.f;
#pragma unroll
        for (int t = 0; t < T_; ++t) {
            const float pt = prow[t];
            h0 = fmaf(w0[t], pt, h0);
            h1 = fmaf(w1[t], pt, h1);
        }
        h0 = fmaxf(fmaf(h0, s0, c0), 0.f);
        h1 = fmaxf(fmaf(h1, s1, c1), 0.f);
        float p0 = wa0 * h0 + wa1 * h1;
        float p1 = wb0 * h0 + wb1 * h1;
        float p2 = wc0 * h0 + wc1 * h1;
#pragma unroll
        for (int off = 32; off > 0; off >>= 1) {
            p0 += __shfl_xor(p0, off);
            p1 += __shfl_xor(p1, off);
            p2 += __shfl_xor(p2, off);
        }
        const float mx = fmaxf(p0, fmaxf(p1, p2));
        const float e0 = expf(p0 - mx), e1 = expf(p1 - mx), e2 = expf(p2 - mx);
        const float inv = 1.0f / (e0 + e1 + e2);
        if (lane < 3) {
            const float val = (lane == 0) ? e0 : (lane == 1) ? e1 : e2;
            kern[(size_t)row * 3 + lane] = val * inv;
        }
    }
}

__global__ __launch_bounds__(256) void kL1(
    const float* __restrict__ pooled, const float* __restrict__ WL1,
    const float* __restrict__ g2, const float* __restrict__ b2,
    const float* __restrict__ m2, const float* __restrict__ v2,
    float* __restrict__ a1) {
    __shared__ float ps[C_ * 66];
    const int n = blockIdx.x >> 2;
    const int bq = blockIdx.x & 3;
    const int w = threadIdx.x >> 6;
    const int t = threadIdx.x & 63;
    const float* pn = pooled + (size_t)n * (C_ * T_);
    for (int e = threadIdx.x; e < C_ * T_; e += 256) {
        const int i = e >> 6, tt = e & 63;
        ps[i * 66 + 1 + tt] = pn[e];
    }
    {
        const int i = threadIdx.x;
        ps[i * 66] = 0.f;
        ps[i * 66 + 65] = 0.f;
    }
    __syncthreads();
    const int ccb = __builtin_amdgcn_readfirstlane(bq * 16 + w * 4);
    const float* __restrict__ wb = WL1 + (size_t)ccb * (C_ * 3);
    float a0 = 0.f, a1v = 0.f, a2 = 0.f, a3 = 0.f;
#pragma unroll 4
    for (int i = 0; i < C_; ++i) {
        const float pm = ps[i * 66 + t];
        const float pc = ps[i * 66 + 1 + t];
        const float pp = ps[i * 66 + 2 + t];
        a0 = fmaf(wb[0 * 768 + i * 3 + 0], pm, fmaf(wb[0 * 768 + i * 3 + 1], pc, fmaf(wb[0 * 768 + i * 3 + 2], pp, a0)));
        a1v = fmaf(wb[1 * 768 + i * 3 + 0], pm, fmaf(wb[1 * 768 + i * 3 + 1], pc, fmaf(wb[1 * 768 + i * 3 + 2], pp, a1v)));
        a2 = fmaf(wb[2 * 768 + i * 3 + 0], pm, fmaf(wb[2 * 768 + i * 3 + 1], pc, fmaf(wb[2 * 768 + i * 3 + 2], pp, a2)));
        a3 = fmaf(wb[3 * 768 + i * 3 + 0], pm, fmaf(wb[3 * 768 + i * 3 + 1], pc, fmaf(wb[3 * 768 + i * 3 + 2], pp, a3)));
    }
    float* ab = a1 + ((size_t)n * C4_ + ccb) * T_ + t;
    const float accv[4] = {a0, a1v, a2, a3};
#pragma unroll
    for (int j = 0; j < 4; ++j) {
        const int cc = ccb + j;
        const float sc = g2[cc] * rsqrtf(v2[cc] + EPSB);
        const float sh = b2[cc] - m2[cc] * sc;
        ab[j * T_] = fmaxf(fmaf(accv[j], sc, sh), 0.f);
    }
}

__global__ __launch_bounds__(256) void kL2(
    const float* __restrict__ a1, const float* __restrict__ WL2,
    float* __restrict__ act) {
    const int n = blockIdx.x >> 4;
    const int bq = blockIdx.x & 15;
    const int w = threadIdx.x >> 6;
    const int t = threadIdx.x & 63;
    const int cb = __builtin_amdgcn_readfirstlane(bq * 16 + w * 4);
    const float* __restrict__ an = a1 + (size_t)n * (C4_ * T_);
    const float* __restrict__ w2 = WL2 + (size_t)cb * C4_;
    float o0 = 0.f, o1 = 0.f, o2 = 0.f, o3 = 0.f;
#pragma unroll 4
    for (int i = 0; i < C4_; ++i) {
        const float av = an[i * T_ + t];
        o0 = fmaf(w2[0 * C4_ + i], av, o0);
        o1 = fmaf(w2[1 * C4_ + i], av, o1);
        o2 = fmaf(w2[2 * C4_ + i], av, o2);
        o3 = fmaf(w2[3 * C4_ + i], av, o3);
    }
    float* ar = act + ((size_t)n * C_ + cb) * T_ + t;
    ar[0 * T_] = 1.0f / (1.0f + expf(-o0));
    ar[1 * T_] = 1.0f / (1.0f + expf(-o1));
    ar[2 * T_] = 1.0f / (1.0f + expf(-o2));
    ar[3 * T_] = 1.0f / (1.0f + expf(-o3));
}

__global__ __launch_bounds__(256) void k_final(const float* __restrict__ x,
                                               const float* __restrict__ act,
                                               const float* __restrict__ kern,
                                               float* __restrict__ out) {
    __shared__ float xs[TV];
    __shared__ float as[T_ + 2];
    const int row = blockIdx.x;
    const float4* xr4 = (const float4*)(x + (size_t)row * TV);
    float4* outr4 = (float4*)(out + (size_t)row * TV);
    float4* xs4 = (float4*)xs;
    for (int f = threadIdx.x; f < TV / 4; f += 256) xs4[f] = xr4[f];
    if (threadIdx.x < T_ + 2) {
        const int t = (int)threadIdx.x - 1;
        as[threadIdx.x] = (t >= 0 && t < T_) ? act[(size_t)row * T_ + t] : 0.f;
    }
    const float k0 = kern[(size_t)row * 3 + 0];
    const float k1 = kern[(size_t)row * 3 + 1];
    const float k2 = kern[(size_t)row * 3 + 2];
    __syncthreads();
    for (int f = threadIdx.x; f < TV / 4; f += 256) {
        float r[4];
#pragma unroll
        for (int q = 0; q < 4; ++q) {
            const int e = f * 4 + q;
            const int t = e / 25;
            const float xc = xs[e];
            const float xm = (t > 0) ? xs[e - 25] : 0.f;
            const float xq = (t < 63) ? xs[e + 25] : 0.f;
            r[q] = xc + k0 * xm * as[t] + k1 * xc * as[t + 1] + k2 * xq * as[t + 2];
        }
        outr4[f] = make_float4(r[0], r[1], r[2], r[3]);
    }
}

// ========================= host launcher =========================
extern "C" void kernel_launch(void* const* d_in, const int* in_sizes, int n_in,
                              void* d_out, int out_size, void* d_ws, size_t ws_size,
                              hipStream_t stream) {
    const float* x   = (const float*)d_in[0];
    const float* Wg1 = (const float*)d_in[1];
    const float* g1  = (const float*)d_in[2];
    const float* b1  = (const float*)d_in[3];
    const float* m1  = (const float*)d_in[4];
    const float* v1  = (const float*)d_in[5];
    const float* Wg2 = (const float*)d_in[6];
    const float* WL1 = (const float*)d_in[7];
    const float* g2  = (const float*)d_in[8];
    const float* b2  = (const float*)d_in[9];
    const float* m2  = (const float*)d_in[10];
    const float* v2  = (const float*)d_in[11];
    const float* WL2 = (const float*)d_in[12];
    float* out = (float*)d_out;

    float* ws = (float*)d_ws;
    float* pooled = ws;                          // NC*T floats (4 MB)
    float* act    = ws + (size_t)NC * T_;        // NC*T floats (4 MB)
    float* kern   = ws + (size_t)2 * NC * T_;    // NC*3 floats
    float* a1buf  = ws + (size_t)2 * NC * T_ + (size_t)NC * 4;  // fallback only

    int nb = 0;
    hipError_t oe = hipOccupancyMaxActiveBlocksPerMultiprocessor(&nb, kfused, 256, 0);
    int grid = (oe == hipSuccess && nb >= 1) ? nb * 256 : 768;   // 256 CUs
    if (grid > 1024) grid = 1024;
    grid &= ~3;
    if (grid < 4) grid = 4;

    void* args[] = {(void*)&x,  (void*)&Wg1, (void*)&g1, (void*)&b1,
                    (void*)&m1, (void*)&v1,  (void*)&Wg2, (void*)&WL1,
                    (void*)&g2, (void*)&b2,  (void*)&m2, (void*)&v2,
                    (void*)&WL2, (void*)&out, (void*)&pooled, (void*)&act,
                    (void*)&kern};
    hipError_t le = hipLaunchCooperativeKernel((void*)kfused, dim3(grid), dim3(256),
                                               args, 0, stream);
    if (le != hipSuccess) {
        // fallback: known-good 5-kernel path
        k_pool   <<<NC / 4, 256, 0, stream>>>(x, pooled);
        k_gbranch<<<512,    256, 0, stream>>>(pooled, Wg1, g1, b1, m1, v1, Wg2, kern);
        kL1      <<<N_ * 4, 256, 0, stream>>>(pooled, WL1, g2, b2, m2, v2, a1buf);
        kL2      <<<N_ * 16, 256, 0, stream>>>(a1buf, WL2, act);
        k_final  <<<NC,     256, 0, stream>>>(x, act, kern, out);
    }
}

// Round 4
// 275.598 us; speedup vs baseline: 1.9837x; 1.9837x over previous
//
#include <hip/hip_runtime.h>
#include <math.h>

#define EPSB 1e-5f

typedef float f32x4 __attribute__((ext_vector_type(4)));

constexpr int N_ = 64, C_ = 256, T_ = 64, V_ = 25, C4_ = 64;
constexpr int NC = N_ * C_;   // 16384
constexpr int TV = T_ * V_;   // 1600

// ---------------- K1: pooled[nc][t] = mean_v x[nc][t][v] ----------------
// 4 rows/block; float4 LDS stage, 256 threads reduce 25 each.
__global__ __launch_bounds__(256) void k_pool(const float* __restrict__ x,
                                              float* __restrict__ pooled) {
    __shared__ float xs[4 * TV];
    const int b = blockIdx.x;
    const float4* xp4 = (const float4*)(x + (size_t)b * (4 * TV));
    float4* xs4 = (float4*)xs;
    for (int f = threadIdx.x; f < TV; f += 256) xs4[f] = xp4[f];
    __syncthreads();
    float s = 0.f;
    const int base = threadIdx.x * V_;   // stride-25: ≤2 lanes/bank, free
#pragma unroll
    for (int v = 0; v < V_; ++v) s += xs[base + v];
    pooled[(size_t)b * 256 + threadIdx.x] = s * (1.0f / 25.0f);
}

// ---------------- K2: fused G + L (role split on blockIdx, no sync dep) --
union GLsm {
    float Wt[64 * 130];                               // G: 33.3 KB
    struct { float ps[C_ * 10]; float a1s[C4_ * 9]; } L;  // L: 12.3 KB
};

__global__ __launch_bounds__(256) void k_GL(
    const float* __restrict__ pooled,
    const float* __restrict__ Wg1, const float* __restrict__ g1,
    const float* __restrict__ b1, const float* __restrict__ m1,
    const float* __restrict__ v1, const float* __restrict__ Wg2,
    const float* __restrict__ WL1, const float* __restrict__ g2,
    const float* __restrict__ b2, const float* __restrict__ m2,
    const float* __restrict__ v2, const float* __restrict__ WL2,
    float* __restrict__ kern, float* __restrict__ act) {
    __shared__ GLsm sm;
    const int tid = threadIdx.x, bid = blockIdx.x;
    const int lane = tid & 63, wv = tid >> 6;

    if (bid < 512) {
        // ======== G branch: blocks 0..511, wave handles 8 (n,c) rows ========
        for (int e = tid; e < 128 * 64; e += 256) {
            const int j = e >> 6, t = e & 63;
            sm.Wt[t * 130 + j] = Wg1[e];      // transposed, pad 130
        }
        __syncthreads();
        const int j0 = lane, j1 = lane + 64;
        const float s0 = g1[j0] * rsqrtf(v1[j0] + EPSB);
        const float s1 = g1[j1] * rsqrtf(v1[j1] + EPSB);
        const float c0 = b1[j0] - m1[j0] * s0;
        const float c1 = b1[j1] - m1[j1] * s1;
        const float wa0 = Wg2[j0], wa1 = Wg2[j1];
        const float wb0 = Wg2[128 + j0], wb1 = Wg2[128 + j1];
        const float wc0 = Wg2[256 + j0], wc1 = Wg2[256 + j1];

        const int r0 = (bid * 4 + wv) * 8;    // 2048 waves x 8 rows = NC
        float pv[8], h0[8], h1[8];
#pragma unroll
        for (int r = 0; r < 8; ++r) {
            pv[r] = pooled[(size_t)(r0 + r) * 64 + lane];
            h0[r] = 0.f; h1[r] = 0.f;
        }
#pragma unroll
        for (int tb = 0; tb < 4; ++tb) {
            float w0[16], w1[16];
#pragma unroll
            for (int tt = 0; tt < 16; ++tt) {
                w0[tt] = sm.Wt[(tb * 16 + tt) * 130 + j0];
                w1[tt] = sm.Wt[(tb * 16 + tt) * 130 + j1];
            }
#pragma unroll
            for (int tt = 0; tt < 16; ++tt) {
#pragma unroll
                for (int r = 0; r < 8; ++r) {
                    const float pt = __uint_as_float(
                        __builtin_amdgcn_readlane(__float_as_uint(pv[r]), tb * 16 + tt));
                    h0[r] = fmaf(w0[tt], pt, h0[r]);
                    h1[r] = fmaf(w1[tt], pt, h1[r]);
                }
            }
        }
#pragma unroll
        for (int r = 0; r < 8; ++r) {
            const float a0 = fmaxf(fmaf(h0[r], s0, c0), 0.f);
            const float a1v = fmaxf(fmaf(h1[r], s1, c1), 0.f);
            float p0 = wa0 * a0 + wa1 * a1v;
            float p1 = wb0 * a0 + wb1 * a1v;
            float p2 = wc0 * a0 + wc1 * a1v;
#pragma unroll
            for (int off = 32; off > 0; off >>= 1) {
                p0 += __shfl_xor(p0, off);
                p1 += __shfl_xor(p1, off);
                p2 += __shfl_xor(p2, off);
            }
            const float mx = fmaxf(p0, fmaxf(p1, p2));
            const float e0 = expf(p0 - mx), e1 = expf(p1 - mx), e2 = expf(p2 - mx);
            const float inv = 1.0f / (e0 + e1 + e2);
            if (lane < 3) {
                const float val = (lane == 0) ? e0 : (lane == 1) ? e1 : e2;
                kern[(size_t)(r0 + r) * 3 + lane] = val * inv;
            }
        }
    } else {
        // ======== L branch: blocks 512..1023 -> (n, 8-t slice) ========
        const int Lb = bid - 512;
        const int n = Lb >> 3;
        const int t0 = (Lb & 7) * 8;
        // stage pooled[n][i][t0-1 .. t0+8] (10 cols, zero halo)
        for (int e = tid; e < C_ * 10; e += 256) {
            const int i = e / 10, tt = e - i * 10;
            const int gt = t0 - 1 + tt;
            sm.L.ps[e] = (gt >= 0 && gt < 64)
                             ? pooled[(size_t)n * 16384 + i * 64 + gt] : 0.f;
        }
        __syncthreads();
        // conv1 (K=3) + BN + ReLU: thread = (cc, t-duo)
        const int cc = tid >> 2;
        const int tq = tid & 3;         // t_local = 2*tq, 2*tq+1
        float acc0 = 0.f, acc1 = 0.f;
        const float* __restrict__ wrow = WL1 + (size_t)cc * 768;
#pragma unroll 4
        for (int i = 0; i < C_; ++i) {
            const float pA = sm.L.ps[i * 10 + 2 * tq + 0];
            const float pB = sm.L.ps[i * 10 + 2 * tq + 1];
            const float pC = sm.L.ps[i * 10 + 2 * tq + 2];
            const float pD = sm.L.ps[i * 10 + 2 * tq + 3];
            const float wk0 = wrow[i * 3 + 0];
            const float wk1 = wrow[i * 3 + 1];
            const float wk2 = wrow[i * 3 + 2];
            acc0 = fmaf(wk0, pA, fmaf(wk1, pB, fmaf(wk2, pC, acc0)));
            acc1 = fmaf(wk0, pB, fmaf(wk1, pC, fmaf(wk2, pD, acc1)));
        }
        const float sc = g2[cc] * rsqrtf(v2[cc] + EPSB);
        const float sh = b2[cc] - m2[cc] * sc;
        sm.L.a1s[cc * 9 + 2 * tq + 0] = fmaxf(fmaf(acc0, sc, sh), 0.f);
        sm.L.a1s[cc * 9 + 2 * tq + 1] = fmaxf(fmaf(acc1, sc, sh), 0.f);
        __syncthreads();
        // conv2 (k=1) + sigmoid: thread = output channel c, 8 t each
        const int c = tid;
        float o[8];
#pragma unroll
        for (int q = 0; q < 8; ++q) o[q] = 0.f;
        const float* __restrict__ w2 = WL2 + (size_t)c * 64;
#pragma unroll 4
        for (int i = 0; i < C4_; ++i) {
            const float w = w2[i];
#pragma unroll
            for (int q = 0; q < 8; ++q)
                o[q] = fmaf(w, sm.L.a1s[i * 9 + q], o[q]);   // broadcast reads
        }
        float* ar = act + ((size_t)n * 256 + c) * 64 + t0;
#pragma unroll
        for (int q = 0; q < 8; ++q) ar[q] = 1.0f / (1.0f + expf(-o[q]));
    }
}

// ---------------- K3: out = x + sum_k kern_k*(x*act)[t+k-1], 4 rows/block
__global__ __launch_bounds__(256) void k_final(const float* __restrict__ x,
                                               const float* __restrict__ act,
                                               const float* __restrict__ kern,
                                               float* __restrict__ out) {
    __shared__ float xs[4 * TV];
    __shared__ float as[4 * 66];   // act[row][t-1..t+64], zero-padded
    __shared__ float ks[12];
    const int b = blockIdx.x;
    const int r0 = b * 4;
    const float4* xr4 = (const float4*)(x + (size_t)b * (4 * TV));
    float4* xs4 = (float4*)xs;
    for (int f = threadIdx.x; f < TV; f += 256) xs4[f] = xr4[f];   // 1600 f4
    for (int e = threadIdx.x; e < 4 * 66; e += 256) {
        const int row = e / 66, tt = e - row * 66;
        const int t = tt - 1;
        as[e] = (t >= 0 && t < 64) ? act[(size_t)(r0 + row) * 64 + t] : 0.f;
    }
    if (threadIdx.x < 12) ks[threadIdx.x] = kern[(size_t)b * 12 + threadIdx.x];
    __syncthreads();
    for (int f = threadIdx.x; f < TV; f += 256) {     // 1600 float4 outputs
        const int row = f / 400;
        const int e0 = (f - row * 400) * 4;
        const int rb = row * TV;
        float r[4];
#pragma unroll
        for (int q = 0; q < 4; ++q) {
            const int e = e0 + q;
            const int t = e / 25;
            const int idx = rb + e;
            const float xc = xs[idx];
            const float xm = (t > 0)  ? xs[idx - 25] : 0.f;
            const float xq = (t < 63) ? xs[idx + 25] : 0.f;
            const float am = as[row * 66 + t];
            const float ac = as[row * 66 + t + 1];
            const float ap = as[row * 66 + t + 2];
            r[q] = fmaf(ks[row * 3 + 0], xm * am,
                   fmaf(ks[row * 3 + 1], xc * ac,
                   fmaf(ks[row * 3 + 2], xq * ap, xc)));
        }
        f32x4 v = {r[0], r[1], r[2], r[3]};
        __builtin_nontemporal_store(v, (f32x4*)(out + (size_t)b * (4 * TV)) + f);
    }
}

// ========================= host launcher =========================
extern "C" void kernel_launch(void* const* d_in, const int* in_sizes, int n_in,
                              void* d_out, int out_size, void* d_ws, size_t ws_size,
                              hipStream_t stream) {
    const float* x   = (const float*)d_in[0];
    const float* Wg1 = (const float*)d_in[1];
    const float* g1  = (const float*)d_in[2];
    const float* b1  = (const float*)d_in[3];
    const float* m1  = (const float*)d_in[4];
    const float* v1  = (const float*)d_in[5];
    const float* Wg2 = (const float*)d_in[6];
    const float* WL1 = (const float*)d_in[7];
    const float* g2  = (const float*)d_in[8];
    const float* b2  = (const float*)d_in[9];
    const float* m2  = (const float*)d_in[10];
    const float* v2  = (const float*)d_in[11];
    const float* WL2 = (const float*)d_in[12];
    float* out = (float*)d_out;

    float* ws = (float*)d_ws;
    float* pooled = ws;                          // NC*T floats (4 MB)
    float* act    = ws + (size_t)NC * T_;        // NC*T floats (4 MB)
    float* kern   = ws + (size_t)2 * NC * T_;    // NC*3 floats

    k_pool <<<NC / 4, 256, 0, stream>>>(x, pooled);
    k_GL   <<<1024,   256, 0, stream>>>(pooled, Wg1, g1, b1, m1, v1, Wg2,
                                        WL1, g2, b2, m2, v2, WL2, kern, act);
    k_final<<<NC / 4, 256, 0, stream>>>(x, act, kern, out);
}